// Round 5
// baseline (391.961 us; speedup 1.0000x reference)
//
#include <hip/hip_runtime.h>
#include <stdint.h>

#define NBATCH 256
#define NQ 900
#define NC 91
#define NQC (NQ * NC)      // 81900
#define NV4 (NQC / 4)      // 20475
#define KSEL 100
#define IOU_THRF 0.7f
#define CONF_THRF 0.3f
#define DELTA 4096u        // key-space tie-safety margin (~1e-3 logit; ties need ~2e-6)

// ---- kernel A (candidate filter, no sort, u32 idx payload) ----
#define SLC 9              // slices per batch
#define SF4 2275           // float4 per slice (9*2275 = 20475 exact)
#define ANT 256
#define ABINS 4096
#define ACH (ABINS / ANT)  // 16
#define CAPB 4096          // per-batch candidate cap (expected ~1100-1900)

// ---- kernel B (gather + prune + sort + NMS) ----
#define BNT 256
#define BBINS 4096
#define BCH (BBINS / BNT)  // 16
#define SRTCAP 1024

// monotone key: ascending uint order == ascending float order
__device__ __forceinline__ uint32_t fkey(float x) {
  uint32_t b = __float_as_uint(x);
  return b ^ ((uint32_t)((int32_t)b >> 31) | 0x80000000u);
}
__device__ __forceinline__ float unfkey(uint32_t k) {
  uint32_t b = (k & 0x80000000u) ? (k ^ 0x80000000u) : ~k;
  return __uint_as_float(b);
}
__device__ __forceinline__ float sigmoidf_ref(float x) {
  return 1.0f / (1.0f + expf(-x));
}

// ======================= kernel A =======================
// Slice lives in registers; LDS hist of 12-bit fkey bins; slice-local cut
// (slice 100th <= batch 100th, so fkey >= cutlo-DELTA supersets this slice's
// share of the batch top-100 incl. prob-rounding ties). Appends u32 indices
// to the per-batch global candidate list.
__global__ __launch_bounds__(ANT) void kfilter(const float* __restrict__ logits,
                                               uint32_t* __restrict__ cnt,
                                               uint32_t* __restrict__ cand) {
  __shared__ uint32_t hist[ABINS];
  __shared__ uint32_t suf[ANT];
  __shared__ uint32_t s_cut;

  const int blk = blockIdx.x;
  const int b = blk / SLC;
  const int s = blk - b * SLC;
  const int tid = threadIdx.x;
  const float4* lg4 = (const float4*)(logits + (size_t)b * NQC) + (size_t)s * SF4;

  for (int i = tid; i < ABINS; i += ANT) hist[i] = 0;
  if (tid == 0) s_cut = 0;
  __syncthreads();

  // load slice into registers, histogram keys
  uint32_t ka[9], kb[9], kc[9], kd[9];
  #pragma unroll
  for (int j = 0; j < 9; j++) {
    const int i = tid + j * ANT;
    const bool v = (i < SF4);
    float4 val = make_float4(0.f, 0.f, 0.f, 0.f);
    if (v) val = lg4[i];
    ka[j] = fkey(val.x);
    kb[j] = fkey(val.y);
    kc[j] = fkey(val.z);
    kd[j] = fkey(val.w);
    if (v) {
      atomicAdd(&hist[ka[j] >> 20], 1u);
      atomicAdd(&hist[kb[j] >> 20], 1u);
      atomicAdd(&hist[kc[j] >> 20], 1u);
      atomicAdd(&hist[kd[j] >> 20], 1u);
    }
  }
  __syncthreads();

  // chunk sums + suffix scan to find local cut bin (100th by logit order)
  uint32_t mine = 0;
  {
    const int base = tid * ACH;
    #pragma unroll
    for (int i = 0; i < ACH; i++) mine += hist[base + i];
    suf[tid] = mine;
  }
  __syncthreads();
  for (int off = 1; off < ANT; off <<= 1) {
    uint32_t v = suf[tid];
    if (tid + off < ANT) v += suf[tid + off];
    __syncthreads();
    suf[tid] = v;
    __syncthreads();
  }
  {
    uint32_t after = suf[tid] - mine;
    if (after < KSEL && after + mine >= KSEL) {   // exactly one thread
      uint32_t run = after;
      const int base = tid * ACH;
      for (int i = ACH - 1; i >= 0; i--) {
        uint32_t h = hist[base + i];
        if (run + h >= KSEL) { s_cut = (uint32_t)(base + i); break; }
        run += h;
      }
    }
  }
  __syncthreads();
  const uint32_t cutlo = s_cut << 20;
  const uint32_t thresh = (cutlo > DELTA) ? (cutlo - DELTA) : 0u;
  const int lane = tid & 63;
  uint32_t* cb = cand + (size_t)b * CAPB;

  // collect from registers with wave-aggregated global atomics
  #pragma unroll
  for (int j = 0; j < 9; j++) {
    const int i = tid + j * ANT;
    const bool v = (i < SF4);
    uint32_t ks[4] = {ka[j], kb[j], kc[j], kd[j]};
    #pragma unroll
    for (int c = 0; c < 4; c++) {
      const bool pred = v && (ks[c] >= thresh);
      unsigned long long mask = __ballot(pred);
      if (mask) {
        int lead = __ffsll((long long)mask) - 1;
        uint32_t tot = (uint32_t)__popcll(mask);
        uint32_t base = 0;
        if (lane == lead) base = atomicAdd(&cnt[b], tot);
        base = (uint32_t)__shfl((int)base, lead);
        if (pred) {
          uint32_t off = (uint32_t)__popcll(mask & ((1ULL << lane) - 1ULL));
          uint32_t pos = base + off;
          if (pos < CAPB)
            cb[pos] = (uint32_t)((s * SF4 + i) * 4 + c);
        }
      }
    }
  }
}

// ======================= kernel B =======================
union BSMem {
  struct {
    uint32_t idxs[CAPB];                           // 16 KB
    uint32_t keys[CAPB];                           // 16 KB
    union {
      uint32_t hist[BBINS];                        // 16 KB
      unsigned long long srt[SRTCAP];              // 8 KB (after cut found)
    } h;
    uint32_t suf[BNT];                             // 1 KB
  } p;
  struct {
    float iou[KSEL * KSEL];                        // 40 KB
    float box[KSEL][4];
    int keep[KSEL];
  } nms;
};

__global__ __launch_bounds__(BNT) void merge_nms(const uint32_t* __restrict__ cnt,
                                                 const uint32_t* __restrict__ cand,
                                                 const float* __restrict__ logits,
                                                 const float* __restrict__ pboxes,
                                                 const float* __restrict__ tsizes,
                                                 float* __restrict__ out) {
  __shared__ BSMem sm;
  __shared__ uint32_t s_cut, s_m;

  const int b = blockIdx.x;
  const int tid = threadIdx.x;
  const uint32_t ntot = cnt[b];
  const uint32_t n = ntot < CAPB ? ntot : CAPB;    // >= 900 structurally

  for (uint32_t i = tid; i < n; i += BNT)
    sm.p.idxs[i] = cand[(size_t)b * CAPB + i];
  for (int i = tid; i < BBINS; i += BNT) sm.p.h.hist[i] = 0;
  if (tid == 0) { s_cut = 0; s_m = 0; }
  __syncthreads();

  // gather logits (L3-resident), compute keys, histogram
  const float* lg = logits + (size_t)b * NQC;
  for (uint32_t i = tid; i < n; i += BNT) {
    uint32_t k = fkey(lg[sm.p.idxs[i]]);
    sm.p.keys[i] = k;
    atomicAdd(&sm.p.h.hist[k >> 20], 1u);
  }
  __syncthreads();

  // suffix scan -> batch cut bin (candidates superset the batch top-100,
  // so their 100th by key == the batch's 100th)
  uint32_t mine = 0;
  {
    const int base = tid * BCH;
    #pragma unroll
    for (int i = 0; i < BCH; i++) mine += sm.p.h.hist[base + i];
    sm.p.suf[tid] = mine;
  }
  __syncthreads();
  for (int off = 1; off < BNT; off <<= 1) {
    uint32_t v = sm.p.suf[tid];
    if (tid + off < BNT) v += sm.p.suf[tid + off];
    __syncthreads();
    sm.p.suf[tid] = v;
    __syncthreads();
  }
  {
    uint32_t after = sm.p.suf[tid] - mine;
    if (after < KSEL && after + mine >= KSEL) {
      uint32_t run = after;
      const int base = tid * BCH;
      for (int i = BCH - 1; i >= 0; i--) {
        uint32_t h = sm.p.h.hist[base + i];
        if (run + h >= KSEL) { s_cut = (uint32_t)(base + i); break; }
        run += h;
      }
    }
  }
  __syncthreads();
  const uint32_t cutlo = s_cut << 20;
  const uint32_t thresh = (cutlo > DELTA) ? (cutlo - DELTA) : 0u;
  __syncthreads();   // all hist/suf reads done before srt (aliases hist) writes

  // compact survivors; sigmoid only here; final key = (~pbits)<<32 | idx
  for (uint32_t i = tid; i < n; i += BNT) {
    uint32_t k = sm.p.keys[i];
    if (k >= thresh) {
      uint32_t pb = __float_as_uint(sigmoidf_ref(unfkey(k)));
      uint32_t pos = atomicAdd(&s_m, 1u);
      if (pos < SRTCAP)
        sm.p.h.srt[pos] = (((unsigned long long)(~pb)) << 32) |
                          (unsigned long long)sm.p.idxs[i];
    }
  }
  __syncthreads();
  const uint32_t m = s_m < SRTCAP ? s_m : SRTCAP;  // ~110-250, >= 100
  uint32_t P = 128;
  while (P < m) P <<= 1;                            // <= 1024
  for (uint32_t i = m + tid; i < P; i += BNT) sm.p.h.srt[i] = ~0ULL;
  __syncthreads();

  // bitonic sort ascending: (prob desc, idx asc)
  for (uint32_t kk = 2; kk <= P; kk <<= 1) {
    for (uint32_t jj = kk >> 1; jj > 0; jj >>= 1) {
      for (uint32_t i = tid; i < P; i += BNT) {
        uint32_t ixj = i ^ jj;
        if (ixj > i) {
          unsigned long long a = sm.p.h.srt[i];
          unsigned long long c = sm.p.h.srt[ixj];
          bool sw = ((i & kk) == 0) ? (a > c) : (a < c);
          if (sw) { sm.p.h.srt[i] = c; sm.p.h.srt[ixj] = a; }
        }
      }
      __syncthreads();
    }
  }

  float score = 0.0f;
  int idx = 0;
  if (tid < KSEL) {
    unsigned long long key = sm.p.h.srt[tid];
    score = __uint_as_float(~(uint32_t)(key >> 32));
    idx = (int)(uint32_t)(key & 0xFFFFFFFFu);
  }
  __syncthreads();   // all srt reads done before nms union reuse

  const float img_h = tsizes[b * 2 + 0];
  const float img_w = tsizes[b * 2 + 1];
  float* out_scores = out;
  float* out_labels = out + (size_t)NBATCH * KSEL;
  float* out_boxes  = out + (size_t)2 * NBATCH * KSEL;
  float* out_keep   = out + (size_t)2 * NBATCH * KSEL + (size_t)NBATCH * KSEL * 4;

  if (tid < KSEL) {
    int q = idx / NC;
    int lab = idx - q * NC;
    const float* pb = pboxes + ((size_t)b * NQ + q) * 4;
    float cx = pb[0], cy = pb[1], w = pb[2], h = pb[3];
    float hw = __fmul_rn(0.5f, w), hh = __fmul_rn(0.5f, h);
    float x0 = __fmul_rn(__fsub_rn(cx, hw), img_w);
    float y0 = __fmul_rn(__fsub_rn(cy, hh), img_h);
    float x1 = __fmul_rn(__fadd_rn(cx, hw), img_w);
    float y1 = __fmul_rn(__fadd_rn(cy, hh), img_h);
    out_scores[(size_t)b * KSEL + tid] = score;
    out_labels[(size_t)b * KSEL + tid] = (float)lab;
    float* ob = out_boxes + ((size_t)b * KSEL + tid) * 4;
    ob[0] = x0; ob[1] = y0; ob[2] = x1; ob[3] = y1;
    sm.nms.box[tid][0] = x0; sm.nms.box[tid][1] = y0;
    sm.nms.box[tid][2] = x1; sm.nms.box[tid][3] = y1;
  }
  __syncthreads();

  for (int e = tid; e < KSEL * KSEL; e += BNT) {
    int i = e / KSEL;
    int j = e - i * KSEL;
    float ax0 = sm.nms.box[i][0], ay0 = sm.nms.box[i][1];
    float ax1 = sm.nms.box[i][2], ay1 = sm.nms.box[i][3];
    float bx0 = sm.nms.box[j][0], by0 = sm.nms.box[j][1];
    float bx1 = sm.nms.box[j][2], by1 = sm.nms.box[j][3];
    float areaA = __fmul_rn(__fsub_rn(ax1, ax0), __fsub_rn(ay1, ay0));
    float areaB = __fmul_rn(__fsub_rn(bx1, bx0), __fsub_rn(by1, by0));
    float ltx = fmaxf(ax0, bx0), lty = fmaxf(ay0, by0);
    float rbx = fminf(ax1, bx1), rby = fminf(ay1, by1);
    float wx = fmaxf(__fsub_rn(rbx, ltx), 0.0f);
    float wy = fmaxf(__fsub_rn(rby, lty), 0.0f);
    float inter = __fmul_rn(wx, wy);
    float uni = __fsub_rn(__fadd_rn(areaA, areaB), inter);
    sm.nms.iou[e] = __fdiv_rn(inter, fmaxf(uni, 1e-9f));
  }
  __syncthreads();

  // sequential NMS inside wave 0 (shfl, no block barriers)
  if (tid < 64) {
    int keepA = 1;
    int keepB = 1;
    for (int i = 0; i < KSEL; i++) {
      int owner = i & 63;
      int ki = (i < 64) ? __shfl(keepA, owner) : __shfl(keepB, owner);
      if (ki) {
        if (tid > i && sm.nms.iou[i * KSEL + tid] > IOU_THRF) keepA = 0;
        int j = tid + 64;
        if (j < KSEL && j > i && sm.nms.iou[i * KSEL + j] > IOU_THRF) keepB = 0;
      }
    }
    sm.nms.keep[tid] = keepA;
    if (tid + 64 < KSEL) sm.nms.keep[tid + 64] = keepB;
  }
  __syncthreads();

  if (tid < KSEL) {
    float kp = (score > CONF_THRF && sm.nms.keep[tid]) ? 1.0f : 0.0f;
    out_keep[(size_t)b * KSEL + tid] = kp;
  }
}

// ======================= fallback: R2 monolithic (known-passing) =======================
#define NBINS 8192
#define NT 1024
#define CHUNK (NBINS / NT)
#define CAP 1024

union MSMem {
  struct {
    uint32_t hist[NBINS];
    unsigned long long cand[CAP];
  } sel;
  struct {
    float iou[KSEL * KSEL];
    float box[KSEL][4];
    int keep[KSEL];
  } nms;
};

__global__ __launch_bounds__(NT) void postproc_mono(const float* __restrict__ logits,
                                                    const float* __restrict__ pboxes,
                                                    const float* __restrict__ tsizes,
                                                    float* __restrict__ out) {
  __shared__ MSMem sm;
  __shared__ uint32_t suf[NT];
  __shared__ uint32_t s_cut, s_above, s_cnt, s_lobin, s_cut2;
  __shared__ uint32_t cand_cnt;

  const int b = blockIdx.x;
  const int tid = threadIdx.x;
  const float4* lg4 = (const float4*)(logits + (size_t)b * NQC);

  for (int i = tid; i < NBINS; i += NT) sm.sel.hist[i] = 0;
  __syncthreads();
  for (int i = tid; i < NV4; i += NT) {
    float4 v = lg4[i];
    atomicAdd(&sm.sel.hist[fkey(v.x) >> 19], 1u);
    atomicAdd(&sm.sel.hist[fkey(v.y) >> 19], 1u);
    atomicAdd(&sm.sel.hist[fkey(v.z) >> 19], 1u);
    atomicAdd(&sm.sel.hist[fkey(v.w) >> 19], 1u);
  }
  __syncthreads();

  uint32_t mine;
  {
    uint32_t s = 0;
    const int base = tid * CHUNK;
    #pragma unroll
    for (int i = 0; i < CHUNK; i++) s += sm.sel.hist[base + i];
    mine = s;
    suf[tid] = s;
  }
  __syncthreads();
  for (int off = 1; off < NT; off <<= 1) {
    uint32_t v = suf[tid];
    if (tid + off < NT) v += suf[tid + off];
    __syncthreads();
    suf[tid] = v;
    __syncthreads();
  }
  {
    uint32_t after = suf[tid] - mine;
    if (after < KSEL && after + mine >= KSEL) {
      uint32_t run = after;
      const int base = tid * CHUNK;
      for (int i = CHUNK - 1; i >= 0; i--) {
        uint32_t h = sm.sel.hist[base + i];
        if (run + h >= KSEL) {
          uint32_t cut = (uint32_t)(base + i);
          uint32_t below = (cut > 0) ? sm.sel.hist[cut - 1] : 0;
          s_cut = cut; s_above = run; s_cnt = h;
          s_lobin = (cut > 0 && run + h + below <= CAP) ? cut - 1 : cut;
          break;
        }
        run += h;
      }
    }
  }
  __syncthreads();
  const uint32_t cut1 = s_cut;
  const uint32_t lobin = s_lobin;
  const bool need2 = (s_above + s_cnt > CAP);
  uint32_t cut2 = 0;

  if (need2) {
    const uint32_t above0 = s_above;
    __syncthreads();
    for (int i = tid; i < NBINS; i += NT) sm.sel.hist[i] = 0;
    __syncthreads();
    for (int i = tid; i < NV4; i += NT) {
      float4 v = lg4[i];
      float xs[4] = {v.x, v.y, v.z, v.w};
      #pragma unroll
      for (int c = 0; c < 4; c++) {
        uint32_t k = fkey(xs[c]);
        if ((k >> 19) == cut1) atomicAdd(&sm.sel.hist[(k >> 6) & 0x1FFFu], 1u);
      }
    }
    __syncthreads();
    {
      uint32_t s = 0;
      const int base = tid * CHUNK;
      #pragma unroll
      for (int i = 0; i < CHUNK; i++) s += sm.sel.hist[base + i];
      mine = s;
      suf[tid] = s;
    }
    __syncthreads();
    for (int off = 1; off < NT; off <<= 1) {
      uint32_t v = suf[tid];
      if (tid + off < NT) v += suf[tid + off];
      __syncthreads();
      suf[tid] = v;
      __syncthreads();
    }
    {
      uint32_t after = above0 + (suf[tid] - mine);
      if (after < KSEL && after + mine >= KSEL) {
        uint32_t run = after;
        const int base = tid * CHUNK;
        for (int i = CHUNK - 1; i >= 0; i--) {
          uint32_t h = sm.sel.hist[base + i];
          if (run + h >= KSEL) { s_cut2 = (uint32_t)(base + i); break; }
          run += h;
        }
      }
    }
    __syncthreads();
    cut2 = s_cut2;
  }

  if (tid == 0) cand_cnt = 0;
  __syncthreads();
  for (int i = tid; i < NV4; i += NT) {
    float4 v = lg4[i];
    float xs[4] = {v.x, v.y, v.z, v.w};
    #pragma unroll
    for (int c = 0; c < 4; c++) {
      uint32_t k = fkey(xs[c]);
      uint32_t b1 = k >> 19;
      bool sel = need2 ? (b1 > cut1 || (b1 == cut1 && ((k >> 6) & 0x1FFFu) >= cut2))
                       : (b1 >= lobin);
      if (sel) {
        uint32_t pbits = __float_as_uint(sigmoidf_ref(xs[c]));
        uint32_t pos = atomicAdd(&cand_cnt, 1u);
        if (pos < CAP)
          sm.sel.cand[pos] = (((unsigned long long)(~pbits)) << 32) |
                             (unsigned long long)(uint32_t)(4 * i + c);
      }
    }
  }
  __syncthreads();
  const uint32_t n = cand_cnt < CAP ? cand_cnt : CAP;
  uint32_t P = 1;
  while (P < n) P <<= 1;
  for (uint32_t i = n + tid; i < P; i += NT) sm.sel.cand[i] = ~0ULL;
  __syncthreads();

  for (uint32_t kk = 2; kk <= P; kk <<= 1) {
    for (uint32_t jj = kk >> 1; jj > 0; jj >>= 1) {
      for (uint32_t i = tid; i < P; i += NT) {
        uint32_t ixj = i ^ jj;
        if (ixj > i) {
          unsigned long long a = sm.sel.cand[i];
          unsigned long long c = sm.sel.cand[ixj];
          bool sw = ((i & kk) == 0) ? (a > c) : (a < c);
          if (sw) { sm.sel.cand[i] = c; sm.sel.cand[ixj] = a; }
        }
      }
      __syncthreads();
    }
  }

  float score = 0.0f;
  int idx = 0;
  if (tid < KSEL) {
    unsigned long long key = sm.sel.cand[tid];
    score = __uint_as_float(~(uint32_t)(key >> 32));
    idx = (int)(uint32_t)(key & 0xFFFFFFFFu);
  }
  __syncthreads();

  const float img_h = tsizes[b * 2 + 0];
  const float img_w = tsizes[b * 2 + 1];
  float* out_scores = out;
  float* out_labels = out + (size_t)NBATCH * KSEL;
  float* out_boxes  = out + (size_t)2 * NBATCH * KSEL;
  float* out_keep   = out + (size_t)2 * NBATCH * KSEL + (size_t)NBATCH * KSEL * 4;

  if (tid < KSEL) {
    int q = idx / NC;
    int lab = idx - q * NC;
    const float* pb = pboxes + ((size_t)b * NQ + q) * 4;
    float cx = pb[0], cy = pb[1], w = pb[2], h = pb[3];
    float hw = __fmul_rn(0.5f, w), hh = __fmul_rn(0.5f, h);
    float x0 = __fmul_rn(__fsub_rn(cx, hw), img_w);
    float y0 = __fmul_rn(__fsub_rn(cy, hh), img_h);
    float x1 = __fmul_rn(__fadd_rn(cx, hw), img_w);
    float y1 = __fmul_rn(__fadd_rn(cy, hh), img_h);
    out_scores[(size_t)b * KSEL + tid] = score;
    out_labels[(size_t)b * KSEL + tid] = (float)lab;
    float* ob = out_boxes + ((size_t)b * KSEL + tid) * 4;
    ob[0] = x0; ob[1] = y0; ob[2] = x1; ob[3] = y1;
    sm.nms.box[tid][0] = x0; sm.nms.box[tid][1] = y0;
    sm.nms.box[tid][2] = x1; sm.nms.box[tid][3] = y1;
  }
  __syncthreads();

  for (int e = tid; e < KSEL * KSEL; e += NT) {
    int i = e / KSEL;
    int j = e - i * KSEL;
    float ax0 = sm.nms.box[i][0], ay0 = sm.nms.box[i][1];
    float ax1 = sm.nms.box[i][2], ay1 = sm.nms.box[i][3];
    float bx0 = sm.nms.box[j][0], by0 = sm.nms.box[j][1];
    float bx1 = sm.nms.box[j][2], by1 = sm.nms.box[j][3];
    float areaA = __fmul_rn(__fsub_rn(ax1, ax0), __fsub_rn(ay1, ay0));
    float areaB = __fmul_rn(__fsub_rn(bx1, bx0), __fsub_rn(by1, by0));
    float ltx = fmaxf(ax0, bx0), lty = fmaxf(ay0, by0);
    float rbx = fminf(ax1, bx1), rby = fminf(ay1, by1);
    float wx = fmaxf(__fsub_rn(rbx, ltx), 0.0f);
    float wy = fmaxf(__fsub_rn(rby, lty), 0.0f);
    float inter = __fmul_rn(wx, wy);
    float uni = __fsub_rn(__fadd_rn(areaA, areaB), inter);
    sm.nms.iou[e] = __fdiv_rn(inter, fmaxf(uni, 1e-9f));
  }
  __syncthreads();

  if (tid < 64) {
    int keepA = 1;
    int keepB = 1;
    for (int i = 0; i < KSEL; i++) {
      int owner = i & 63;
      int ki = (i < 64) ? __shfl(keepA, owner) : __shfl(keepB, owner);
      if (ki) {
        if (tid > i && sm.nms.iou[i * KSEL + tid] > IOU_THRF) keepA = 0;
        int j = tid + 64;
        if (j < KSEL && j > i && sm.nms.iou[i * KSEL + j] > IOU_THRF) keepB = 0;
      }
    }
    sm.nms.keep[tid] = keepA;
    if (tid + 64 < KSEL) sm.nms.keep[tid + 64] = keepB;
  }
  __syncthreads();

  if (tid < KSEL) {
    float kp = (score > CONF_THRF && sm.nms.keep[tid]) ? 1.0f : 0.0f;
    out_keep[(size_t)b * KSEL + tid] = kp;
  }
}

extern "C" void kernel_launch(void* const* d_in, const int* in_sizes, int n_in,
                              void* d_out, int out_size, void* d_ws, size_t ws_size,
                              hipStream_t stream) {
  const float* logits = (const float*)d_in[0];   // (256, 900, 91) f32
  const float* pboxes = (const float*)d_in[1];   // (256, 900, 4)  f32
  const float* tsizes = (const float*)d_in[2];   // (256, 2)       f32
  (void)in_sizes; (void)n_in; (void)out_size;

  const size_t cnt_bytes = 1024;                                     // 256 u32, padded
  const size_t need = cnt_bytes + (size_t)NBATCH * CAPB * sizeof(uint32_t); // ~4.2 MB
  if (ws_size >= need) {
    uint32_t* cnt = (uint32_t*)d_ws;
    uint32_t* cand = (uint32_t*)((char*)d_ws + cnt_bytes);
    hipMemsetAsync(d_ws, 0, cnt_bytes, stream);                      // zero counters each call
    kfilter<<<NBATCH * SLC, ANT, 0, stream>>>(logits, cnt, cand);
    merge_nms<<<NBATCH, BNT, 0, stream>>>(cnt, cand, logits, pboxes, tsizes, (float*)d_out);
  } else {
    postproc_mono<<<NBATCH, NT, 0, stream>>>(logits, pboxes, tsizes, (float*)d_out);
  }
}

// Round 6
// 77.813 us; speedup vs baseline: 5.0372x; 5.0372x over previous
//
#include <hip/hip_runtime.h>
#include <stdint.h>

#define NBATCH 256
#define NQ 900
#define NC 91
#define NQC (NQ * NC)      // 81900
#define KSEL 100
#define IOU_THRF 0.7f
#define CONF_THRF 0.3f
#define TH_LOGIT 2.2f      // static filter; batch 100th logit ~3.03 (31-sigma margin), verified in-kernel
#define DELTA 4096u        // key-ulp tie margin (~1e-3 logit; prob-rounding ties need ~1.3e-6)

// ---- kernel A: streaming filter ----
#define SLC 25             // slices per batch
#define SF4 819            // float4 per slice (25*819 = 20475 exact)
#define ANT 256
#define LCAP 256           // per-slice LDS candidate cap (expected ~46, 30-sigma margin)
#define CAPB 4096          // per-batch candidate cap (expected ~1139)

// ---- kernel B: select + NMS ----
#define BNT 256
#define BBINS 1024         // bin = (key>>16) - 0xC000, valid for logit in [2.2, 512)
#define BCH (BBINS / BNT)  // 4
#define SRTCAP 512

// monotone key: ascending uint order == ascending float order
__device__ __forceinline__ uint32_t fkey(float x) {
  uint32_t b = __float_as_uint(x);
  return b ^ ((uint32_t)((int32_t)b >> 31) | 0x80000000u);
}
__device__ __forceinline__ float unfkey(uint32_t k) {
  uint32_t b = (k & 0x80000000u) ? (k ^ 0x80000000u) : ~k;
  return __uint_as_float(b);
}
__device__ __forceinline__ float sigmoidf_ref(float x) {
  return 1.0f / (1.0f + expf(-x));
}

// ======================= kernel A =======================
// Pure streaming: keep idx where logit >= TH_LOGIT. LDS compact buffer,
// one global atomicAdd per block, coalesced copy-out. Overflow poisons
// cnt[b] past CAPB so kernel B takes its exact fallback path.
__global__ __launch_bounds__(ANT) void kfilter(const float* __restrict__ logits,
                                               uint32_t* __restrict__ cnt,
                                               uint32_t* __restrict__ cand) {
  __shared__ uint32_t lbuf[LCAP];
  __shared__ uint32_t lcnt, lbase;

  const int blk = blockIdx.x;
  const int b = blk / SLC;
  const int s = blk - b * SLC;
  const int tid = threadIdx.x;
  const float4* lg4 = (const float4*)(logits + (size_t)b * NQC) + (size_t)s * SF4;

  if (tid == 0) lcnt = 0;
  __syncthreads();

  for (int i = tid; i < SF4; i += ANT) {
    float4 v = lg4[i];
    const uint32_t ibase = (uint32_t)((s * SF4 + i) * 4);
    if (v.x >= TH_LOGIT) { uint32_t p = atomicAdd(&lcnt, 1u); if (p < LCAP) lbuf[p] = ibase + 0; }
    if (v.y >= TH_LOGIT) { uint32_t p = atomicAdd(&lcnt, 1u); if (p < LCAP) lbuf[p] = ibase + 1; }
    if (v.z >= TH_LOGIT) { uint32_t p = atomicAdd(&lcnt, 1u); if (p < LCAP) lbuf[p] = ibase + 2; }
    if (v.w >= TH_LOGIT) { uint32_t p = atomicAdd(&lcnt, 1u); if (p < LCAP) lbuf[p] = ibase + 3; }
  }
  __syncthreads();
  const uint32_t m = lcnt;                       // uniform
  if (tid == 0) {
    if (m <= LCAP) lbase = atomicAdd(&cnt[b], m);
    else          atomicAdd(&cnt[b], (uint32_t)(CAPB + 1));   // poison -> fallback
  }
  __syncthreads();
  if (m > LCAP) return;                           // uniform exit
  const uint32_t base = lbase;
  for (uint32_t i = tid; i < m; i += ANT) {
    uint32_t pos = base + i;
    if (pos < CAPB) cand[(size_t)b * CAPB + pos] = lbuf[i];
  }
}

// ======================= kernel B =======================
union BSMem {
  struct {
    uint32_t idxs[CAPB];                          // 16 KB
    uint32_t keys[CAPB];                          // 16 KB
    union {
      struct { uint32_t hist[BBINS]; uint32_t suf[BNT]; } h;  // 5 KB
      unsigned long long srt[SRTCAP];             // 4 KB (aliases hist after cut found)
    } u;
  } p;
  struct {
    float iou[KSEL * KSEL];                       // 40 KB
    float box[KSEL][4];
    int keep[KSEL];
  } nms;
};

__global__ __launch_bounds__(BNT) void merge_nms(const uint32_t* __restrict__ cnt,
                                                 const uint32_t* __restrict__ cand,
                                                 const float* __restrict__ logits,
                                                 const float* __restrict__ pboxes,
                                                 const float* __restrict__ tsizes,
                                                 float* __restrict__ out,
                                                 int force_fallback) {
  __shared__ BSMem sm;
  __shared__ uint32_t s_cut, s_m;
  __shared__ unsigned long long red[BNT / 64];
  __shared__ unsigned long long s_last;

  const int b = blockIdx.x;
  const int tid = threadIdx.x;
  const float* lg = logits + (size_t)b * NQC;

  bool good = !force_fallback;
  uint32_t n = 0;
  if (good) {
    n = cnt[b];
    good = (n >= KSEL && n <= CAPB);
  }

  if (good) {
    for (uint32_t i = tid; i < n; i += BNT)
      sm.p.idxs[i] = cand[(size_t)b * CAPB + i];
    for (int i = tid; i < BBINS; i += BNT) sm.p.u.h.hist[i] = 0;
    if (tid == 0) { s_cut = 0; s_m = 0; }
    __syncthreads();

    // gather logits (L3-hot), key + hist. All keys >= fkey(2.2) = 0xC00CCCCD.
    for (uint32_t i = tid; i < n; i += BNT) {
      uint32_t k = fkey(lg[sm.p.idxs[i]]);
      sm.p.keys[i] = k;
      uint32_t bin = (k >> 16) - 0xC000u;
      if (bin > BBINS - 1) bin = BBINS - 1;
      atomicAdd(&sm.p.u.h.hist[bin], 1u);
    }
    __syncthreads();

    // suffix scan -> cut bin holding the batch 100th (candidates superset top-100)
    uint32_t mine = 0;
    {
      const int base = tid * BCH;
      #pragma unroll
      for (int i = 0; i < BCH; i++) mine += sm.p.u.h.hist[base + i];
      sm.p.u.h.suf[tid] = mine;
    }
    __syncthreads();
    for (int off = 1; off < BNT; off <<= 1) {
      uint32_t v = sm.p.u.h.suf[tid];
      if (tid + off < BNT) v += sm.p.u.h.suf[tid + off];
      __syncthreads();
      sm.p.u.h.suf[tid] = v;
      __syncthreads();
    }
    {
      uint32_t after = sm.p.u.h.suf[tid] - mine;
      if (after < KSEL && after + mine >= KSEL) {   // exactly one thread
        uint32_t run = after;
        const int base = tid * BCH;
        for (int i = BCH - 1; i >= 0; i--) {
          uint32_t h = sm.p.u.h.hist[base + i];
          if (run + h >= KSEL) { s_cut = (uint32_t)(base + i); break; }
          run += h;
        }
      }
    }
    __syncthreads();
    const uint32_t cut = s_cut;
    if (cut >= BBINS - 1) good = false;             // clamped bin: low edge unknown
    const uint32_t cutlo = (cut + 0xC000u) << 16;
    const uint32_t thresh = cutlo - DELTA;          // cutlo >= 0xC00C0000 >> DELTA
    __syncthreads();                                 // hist/suf reads done before srt writes

    if (good) {
      // compact survivors; sigmoid only here; key = (~pbits)<<32 | idx
      for (uint32_t i = tid; i < n; i += BNT) {
        uint32_t k = sm.p.keys[i];
        if (k >= thresh) {
          uint32_t pb = __float_as_uint(sigmoidf_ref(unfkey(k)));
          uint32_t pos = atomicAdd(&s_m, 1u);
          if (pos < SRTCAP)
            sm.p.u.srt[pos] = (((unsigned long long)(~pb)) << 32) |
                              (unsigned long long)sm.p.idxs[i];
        }
      }
      __syncthreads();
      const uint32_t m = s_m;
      if (m > SRTCAP) good = false;
      if (good) {
        uint32_t P = 128;
        while (P < m) P <<= 1;                      // typically 128
        for (uint32_t i = m + tid; i < P; i += BNT) sm.p.u.srt[i] = ~0ULL;
        __syncthreads();
        // bitonic sort ascending: (prob desc, idx asc)
        for (uint32_t kk = 2; kk <= P; kk <<= 1) {
          for (uint32_t jj = kk >> 1; jj > 0; jj >>= 1) {
            for (uint32_t i = tid; i < P; i += BNT) {
              uint32_t ixj = i ^ jj;
              if (ixj > i) {
                unsigned long long a = sm.p.u.srt[i];
                unsigned long long c = sm.p.u.srt[ixj];
                bool sw = ((i & kk) == 0) ? (a > c) : (a < c);
                if (sw) { sm.p.u.srt[i] = c; sm.p.u.srt[ixj] = a; }
              }
            }
            __syncthreads();
          }
        }
      }
    }
  }

  if (!good) {
    // exact fallback (never taken on bench data): 100 rounds of block-wide
    // "next element in (prob desc, idx asc) order" over all 81900 logits.
    unsigned long long last = ~0ULL;
    for (int r = 0; r < KSEL; r++) {
      unsigned long long best = 0ULL;
      for (int i = tid; i < NQC; i += BNT) {
        uint32_t pb = __float_as_uint(sigmoidf_ref(lg[i]));
        unsigned long long cmp = (((unsigned long long)pb) << 32) |
                                 (unsigned long long)(~(uint32_t)i);
        if (cmp < last && cmp > best) best = cmp;
      }
      #pragma unroll
      for (int o = 32; o >= 1; o >>= 1) {
        unsigned long long other = __shfl_down(best, o);
        if (other > best) best = other;
      }
      if ((tid & 63) == 0) red[tid >> 6] = best;
      __syncthreads();
      if (tid == 0) {
        unsigned long long mx = red[0];
        for (int w = 1; w < BNT / 64; w++) if (red[w] > mx) mx = red[w];
        s_last = mx;
        uint32_t pb = (uint32_t)(mx >> 32);
        uint32_t id = ~(uint32_t)mx;
        sm.p.u.srt[r] = (((unsigned long long)(~pb)) << 32) | (unsigned long long)id;
      }
      __syncthreads();
      last = s_last;
    }
  }

  float score = 0.0f;
  int idx = 0;
  if (tid < KSEL) {
    unsigned long long key = sm.p.u.srt[tid];
    score = __uint_as_float(~(uint32_t)(key >> 32));
    idx = (int)(uint32_t)(key & 0xFFFFFFFFu);
  }
  __syncthreads();   // all srt reads done before nms union reuse

  const float img_h = tsizes[b * 2 + 0];
  const float img_w = tsizes[b * 2 + 1];
  float* out_scores = out;
  float* out_labels = out + (size_t)NBATCH * KSEL;
  float* out_boxes  = out + (size_t)2 * NBATCH * KSEL;
  float* out_keep   = out + (size_t)2 * NBATCH * KSEL + (size_t)NBATCH * KSEL * 4;

  if (tid < KSEL) {
    int q = idx / NC;
    int lab = idx - q * NC;
    const float* pb = pboxes + ((size_t)b * NQ + q) * 4;
    float cx = pb[0], cy = pb[1], w = pb[2], h = pb[3];
    float hw = __fmul_rn(0.5f, w), hh = __fmul_rn(0.5f, h);
    float x0 = __fmul_rn(__fsub_rn(cx, hw), img_w);
    float y0 = __fmul_rn(__fsub_rn(cy, hh), img_h);
    float x1 = __fmul_rn(__fadd_rn(cx, hw), img_w);
    float y1 = __fmul_rn(__fadd_rn(cy, hh), img_h);
    out_scores[(size_t)b * KSEL + tid] = score;
    out_labels[(size_t)b * KSEL + tid] = (float)lab;
    float* ob = out_boxes + ((size_t)b * KSEL + tid) * 4;
    ob[0] = x0; ob[1] = y0; ob[2] = x1; ob[3] = y1;
    sm.nms.box[tid][0] = x0; sm.nms.box[tid][1] = y0;
    sm.nms.box[tid][2] = x1; sm.nms.box[tid][3] = y1;
  }
  __syncthreads();

  for (int e = tid; e < KSEL * KSEL; e += BNT) {
    int i = e / KSEL;
    int j = e - i * KSEL;
    float ax0 = sm.nms.box[i][0], ay0 = sm.nms.box[i][1];
    float ax1 = sm.nms.box[i][2], ay1 = sm.nms.box[i][3];
    float bx0 = sm.nms.box[j][0], by0 = sm.nms.box[j][1];
    float bx1 = sm.nms.box[j][2], by1 = sm.nms.box[j][3];
    float areaA = __fmul_rn(__fsub_rn(ax1, ax0), __fsub_rn(ay1, ay0));
    float areaB = __fmul_rn(__fsub_rn(bx1, bx0), __fsub_rn(by1, by0));
    float ltx = fmaxf(ax0, bx0), lty = fmaxf(ay0, by0);
    float rbx = fminf(ax1, bx1), rby = fminf(ay1, by1);
    float wx = fmaxf(__fsub_rn(rbx, ltx), 0.0f);
    float wy = fmaxf(__fsub_rn(rby, lty), 0.0f);
    float inter = __fmul_rn(wx, wy);
    float uni = __fsub_rn(__fadd_rn(areaA, areaB), inter);
    sm.nms.iou[e] = __fdiv_rn(inter, fmaxf(uni, 1e-9f));
  }
  __syncthreads();

  // sequential NMS inside wave 0 (shfl, no block barriers)
  if (tid < 64) {
    int keepA = 1;
    int keepB = 1;
    for (int i = 0; i < KSEL; i++) {
      int owner = i & 63;
      int ki = (i < 64) ? __shfl(keepA, owner) : __shfl(keepB, owner);
      if (ki) {
        if (tid > i && sm.nms.iou[i * KSEL + tid] > IOU_THRF) keepA = 0;
        int j = tid + 64;
        if (j < KSEL && j > i && sm.nms.iou[i * KSEL + j] > IOU_THRF) keepB = 0;
      }
    }
    sm.nms.keep[tid] = keepA;
    if (tid + 64 < KSEL) sm.nms.keep[tid + 64] = keepB;
  }
  __syncthreads();

  if (tid < KSEL) {
    float kp = (score > CONF_THRF && sm.nms.keep[tid]) ? 1.0f : 0.0f;
    out_keep[(size_t)b * KSEL + tid] = kp;
  }
}

extern "C" void kernel_launch(void* const* d_in, const int* in_sizes, int n_in,
                              void* d_out, int out_size, void* d_ws, size_t ws_size,
                              hipStream_t stream) {
  const float* logits = (const float*)d_in[0];   // (256, 900, 91) f32
  const float* pboxes = (const float*)d_in[1];   // (256, 900, 4)  f32
  const float* tsizes = (const float*)d_in[2];   // (256, 2)       f32
  (void)in_sizes; (void)n_in; (void)out_size;

  const size_t cnt_bytes = 1024;                                          // 256 u32, padded
  const size_t need = cnt_bytes + (size_t)NBATCH * CAPB * sizeof(uint32_t); // ~4.2 MB
  if (ws_size >= need) {
    uint32_t* cnt = (uint32_t*)d_ws;
    uint32_t* cand = (uint32_t*)((char*)d_ws + cnt_bytes);
    hipMemsetAsync(d_ws, 0, cnt_bytes, stream);
    kfilter<<<NBATCH * SLC, ANT, 0, stream>>>(logits, cnt, cand);
    merge_nms<<<NBATCH, BNT, 0, stream>>>(cnt, cand, logits, pboxes, tsizes,
                                          (float*)d_out, 0);
  } else {
    // no workspace: exact (slow) fallback path, still correct
    merge_nms<<<NBATCH, BNT, 0, stream>>>(nullptr, nullptr, logits, pboxes, tsizes,
                                          (float*)d_out, 1);
  }
}

// Round 7
// 60.100 us; speedup vs baseline: 6.5218x; 1.2947x over previous
//
#include <hip/hip_runtime.h>
#include <stdint.h>

#define NBATCH 256
#define NQ 900
#define NC 91
#define NQC (NQ * NC)      // 81900
#define KSEL 100
#define IOU_THRF 0.7f
#define CONF_THRF 0.3f
#define TH_LOGIT 2.2f      // static filter; batch 100th logit ~3.03; verified in-kernel
#define DELTA 4096u        // key-ulp tie margin (~1e-3 logit; prob-rounding ties need ~1.3e-6)

// ---- kernel A: streaming filter, deterministic per-slice output ----
#define SLC 25             // slices per batch
#define SF4 819            // float4 per slice (25*819 = 20475 exact)
#define ANT 256
#define SCAP 128           // per-slice cap (expected ~46, 12-sigma margin)
#define CAPB (SLC * SCAP)  // 3200 max gathered per batch

// ---- kernel B: select + NMS ----
#define BNT 256
#define BBINS 1024         // bin = (key>>16) - 0xC000, valid for logit in [2.2, 512)
#define BCH (BBINS / BNT)  // 4
#define SRTCAP 512

// monotone key: ascending uint order == ascending float order
__device__ __forceinline__ uint32_t fkey(float x) {
  uint32_t b = __float_as_uint(x);
  return b ^ ((uint32_t)((int32_t)b >> 31) | 0x80000000u);
}
__device__ __forceinline__ float unfkey(uint32_t k) {
  uint32_t b = (k & 0x80000000u) ? (k ^ 0x80000000u) : ~k;
  return __uint_as_float(b);
}
__device__ __forceinline__ float sigmoidf_ref(float x) {
  return 1.0f / (1.0f + expf(-x));
}

// ======================= kernel A =======================
// Keep idx where logit >= TH_LOGIT. LDS compact buffer, then write count +
// indices to this slice's PRIVATE region. No global atomics, no init needed:
// every slot consumed by kernel B is written fresh each call.
__global__ __launch_bounds__(ANT) void kfilter(const float* __restrict__ logits,
                                               uint32_t* __restrict__ cnts,
                                               uint32_t* __restrict__ cand) {
  __shared__ uint32_t lbuf[SCAP];
  __shared__ uint32_t lcnt;

  const int blk = blockIdx.x;            // b*SLC + s
  const int b = blk / SLC;
  const int s = blk - b * SLC;
  const int tid = threadIdx.x;
  const float4* lg4 = (const float4*)(logits + (size_t)b * NQC) + (size_t)s * SF4;

  if (tid == 0) lcnt = 0;
  __syncthreads();

  for (int i = tid; i < SF4; i += ANT) {
    float4 v = lg4[i];
    const uint32_t ibase = (uint32_t)((s * SF4 + i) * 4);
    if (v.x >= TH_LOGIT) { uint32_t p = atomicAdd(&lcnt, 1u); if (p < SCAP) lbuf[p] = ibase + 0; }
    if (v.y >= TH_LOGIT) { uint32_t p = atomicAdd(&lcnt, 1u); if (p < SCAP) lbuf[p] = ibase + 1; }
    if (v.z >= TH_LOGIT) { uint32_t p = atomicAdd(&lcnt, 1u); if (p < SCAP) lbuf[p] = ibase + 2; }
    if (v.w >= TH_LOGIT) { uint32_t p = atomicAdd(&lcnt, 1u); if (p < SCAP) lbuf[p] = ibase + 3; }
  }
  __syncthreads();
  const uint32_t m = lcnt;               // uniform; > SCAP signals fallback to B
  if (tid == 0) cnts[blk] = m;
  const uint32_t mw = m < SCAP ? m : SCAP;
  for (uint32_t i = tid; i < mw; i += ANT)
    cand[(size_t)blk * SCAP + i] = lbuf[i];
}

// ======================= kernel B =======================
union BSMem {
  struct {
    uint32_t idxs[CAPB];                          // 12.8 KB
    uint32_t keys[CAPB];                          // 12.8 KB
    union {
      struct { uint32_t hist[BBINS]; uint32_t suf[BNT]; } h;  // 5 KB
      unsigned long long srt[SRTCAP];             // 4 KB (aliases hist after cut found)
    } u;
  } p;
  struct {
    float iou[KSEL * KSEL];                       // 40 KB
    float box[KSEL][4];
    int keep[KSEL];
  } nms;
};

__global__ __launch_bounds__(BNT) void merge_nms(const uint32_t* __restrict__ cnts,
                                                 const uint32_t* __restrict__ cand,
                                                 const float* __restrict__ logits,
                                                 const float* __restrict__ pboxes,
                                                 const float* __restrict__ tsizes,
                                                 float* __restrict__ out,
                                                 int force_fallback) {
  __shared__ BSMem sm;
  __shared__ uint32_t scnt[SLC], soff[SLC];
  __shared__ uint32_t s_n, s_bad, s_cut, s_m;
  __shared__ unsigned long long red[BNT / 64];
  __shared__ unsigned long long s_last;

  const int b = blockIdx.x;
  const int tid = threadIdx.x;
  const float* lg = logits + (size_t)b * NQC;

  bool good = !force_fallback;
  if (good) {
    if (tid < SLC) scnt[tid] = cnts[b * SLC + tid];
    if (tid == 0) s_bad = 0;
    __syncthreads();
    if (tid == 0) {
      uint32_t off = 0, bad = 0;
      for (int i = 0; i < SLC; i++) {
        soff[i] = off;
        if (scnt[i] > SCAP) bad = 1;
        off += scnt[i];
      }
      s_n = off;
      s_bad = bad | (off < KSEL ? 1u : 0u);
    }
    __syncthreads();
    good = (s_bad == 0);
  }
  const uint32_t n = good ? s_n : 0;     // <= CAPB structurally

  if (good) {
    // gather slice regions into contiguous LDS list (wave w takes slices w, w+4, ...)
    const int wid = tid >> 6, lane = tid & 63;
    for (int sl = wid; sl < SLC; sl += BNT / 64) {
      const uint32_t c = scnt[sl], o = soff[sl];
      for (uint32_t j = lane; j < c; j += 64)
        sm.p.idxs[o + j] = cand[((size_t)b * SLC + sl) * SCAP + j];
    }
    for (int i = tid; i < BBINS; i += BNT) sm.p.u.h.hist[i] = 0;
    if (tid == 0) { s_cut = 0; s_m = 0; }
    __syncthreads();

    // gather logits (L3-hot), key + hist. All keys >= fkey(2.2) = 0xC00CCCCD.
    for (uint32_t i = tid; i < n; i += BNT) {
      uint32_t k = fkey(lg[sm.p.idxs[i]]);
      sm.p.keys[i] = k;
      uint32_t bin = (k >> 16) - 0xC000u;
      if (bin > BBINS - 1) bin = BBINS - 1;
      atomicAdd(&sm.p.u.h.hist[bin], 1u);
    }
    __syncthreads();

    // suffix scan -> cut bin holding the batch 100th (candidates superset top-100)
    uint32_t mine = 0;
    {
      const int base = tid * BCH;
      #pragma unroll
      for (int i = 0; i < BCH; i++) mine += sm.p.u.h.hist[base + i];
      sm.p.u.h.suf[tid] = mine;
    }
    __syncthreads();
    for (int off = 1; off < BNT; off <<= 1) {
      uint32_t v = sm.p.u.h.suf[tid];
      if (tid + off < BNT) v += sm.p.u.h.suf[tid + off];
      __syncthreads();
      sm.p.u.h.suf[tid] = v;
      __syncthreads();
    }
    {
      uint32_t after = sm.p.u.h.suf[tid] - mine;
      if (after < KSEL && after + mine >= KSEL) {   // exactly one thread
        uint32_t run = after;
        const int base = tid * BCH;
        for (int i = BCH - 1; i >= 0; i--) {
          uint32_t h = sm.p.u.h.hist[base + i];
          if (run + h >= KSEL) { s_cut = (uint32_t)(base + i); break; }
          run += h;
        }
      }
    }
    __syncthreads();
    const uint32_t cut = s_cut;
    if (cut >= BBINS - 1) good = false;             // clamped bin: low edge unknown
    const uint32_t cutlo = (cut + 0xC000u) << 16;
    const uint32_t thresh = cutlo - DELTA;          // cutlo >= 0xC00C0000 >> DELTA
    __syncthreads();                                 // hist/suf reads done before srt writes

    if (good) {
      // compact survivors; sigmoid only here; key = (~pbits)<<32 | idx
      for (uint32_t i = tid; i < n; i += BNT) {
        uint32_t k = sm.p.keys[i];
        if (k >= thresh) {
          uint32_t pb = __float_as_uint(sigmoidf_ref(unfkey(k)));
          uint32_t pos = atomicAdd(&s_m, 1u);
          if (pos < SRTCAP)
            sm.p.u.srt[pos] = (((unsigned long long)(~pb)) << 32) |
                              (unsigned long long)sm.p.idxs[i];
        }
      }
      __syncthreads();
      const uint32_t m = s_m;
      if (m > SRTCAP) good = false;
      if (good) {
        uint32_t P = 128;
        while (P < m) P <<= 1;                      // typically 128
        for (uint32_t i = m + tid; i < P; i += BNT) sm.p.u.srt[i] = ~0ULL;
        __syncthreads();
        // bitonic sort ascending: (prob desc, idx asc)
        for (uint32_t kk = 2; kk <= P; kk <<= 1) {
          for (uint32_t jj = kk >> 1; jj > 0; jj >>= 1) {
            for (uint32_t i = tid; i < P; i += BNT) {
              uint32_t ixj = i ^ jj;
              if (ixj > i) {
                unsigned long long a = sm.p.u.srt[i];
                unsigned long long c = sm.p.u.srt[ixj];
                bool sw = ((i & kk) == 0) ? (a > c) : (a < c);
                if (sw) { sm.p.u.srt[i] = c; sm.p.u.srt[ixj] = a; }
              }
            }
            __syncthreads();
          }
        }
      }
    }
  }

  if (!good) {
    // exact fallback (never taken on bench data): 100 rounds of block-wide
    // "next element in (prob desc, idx asc) order" over all 81900 logits.
    unsigned long long last = ~0ULL;
    for (int r = 0; r < KSEL; r++) {
      unsigned long long best = 0ULL;
      for (int i = tid; i < NQC; i += BNT) {
        uint32_t pb = __float_as_uint(sigmoidf_ref(lg[i]));
        unsigned long long cmp = (((unsigned long long)pb) << 32) |
                                 (unsigned long long)(~(uint32_t)i);
        if (cmp < last && cmp > best) best = cmp;
      }
      #pragma unroll
      for (int o = 32; o >= 1; o >>= 1) {
        unsigned long long other = __shfl_down(best, o);
        if (other > best) best = other;
      }
      if ((tid & 63) == 0) red[tid >> 6] = best;
      __syncthreads();
      if (tid == 0) {
        unsigned long long mx = red[0];
        for (int w = 1; w < BNT / 64; w++) if (red[w] > mx) mx = red[w];
        s_last = mx;
        uint32_t pb = (uint32_t)(mx >> 32);
        uint32_t id = ~(uint32_t)mx;
        sm.p.u.srt[r] = (((unsigned long long)(~pb)) << 32) | (unsigned long long)id;
      }
      __syncthreads();
      last = s_last;
    }
  }

  float score = 0.0f;
  int idx = 0;
  if (tid < KSEL) {
    unsigned long long key = sm.p.u.srt[tid];
    score = __uint_as_float(~(uint32_t)(key >> 32));
    idx = (int)(uint32_t)(key & 0xFFFFFFFFu);
  }
  __syncthreads();   // all srt reads done before nms union reuse

  const float img_h = tsizes[b * 2 + 0];
  const float img_w = tsizes[b * 2 + 1];
  float* out_scores = out;
  float* out_labels = out + (size_t)NBATCH * KSEL;
  float* out_boxes  = out + (size_t)2 * NBATCH * KSEL;
  float* out_keep   = out + (size_t)2 * NBATCH * KSEL + (size_t)NBATCH * KSEL * 4;

  if (tid < KSEL) {
    int q = idx / NC;
    int lab = idx - q * NC;
    const float* pb = pboxes + ((size_t)b * NQ + q) * 4;
    float cx = pb[0], cy = pb[1], w = pb[2], h = pb[3];
    float hw = __fmul_rn(0.5f, w), hh = __fmul_rn(0.5f, h);
    float x0 = __fmul_rn(__fsub_rn(cx, hw), img_w);
    float y0 = __fmul_rn(__fsub_rn(cy, hh), img_h);
    float x1 = __fmul_rn(__fadd_rn(cx, hw), img_w);
    float y1 = __fmul_rn(__fadd_rn(cy, hh), img_h);
    out_scores[(size_t)b * KSEL + tid] = score;
    out_labels[(size_t)b * KSEL + tid] = (float)lab;
    float* ob = out_boxes + ((size_t)b * KSEL + tid) * 4;
    ob[0] = x0; ob[1] = y0; ob[2] = x1; ob[3] = y1;
    sm.nms.box[tid][0] = x0; sm.nms.box[tid][1] = y0;
    sm.nms.box[tid][2] = x1; sm.nms.box[tid][3] = y1;
  }
  __syncthreads();

  for (int e = tid; e < KSEL * KSEL; e += BNT) {
    int i = e / KSEL;
    int j = e - i * KSEL;
    float ax0 = sm.nms.box[i][0], ay0 = sm.nms.box[i][1];
    float ax1 = sm.nms.box[i][2], ay1 = sm.nms.box[i][3];
    float bx0 = sm.nms.box[j][0], by0 = sm.nms.box[j][1];
    float bx1 = sm.nms.box[j][2], by1 = sm.nms.box[j][3];
    float areaA = __fmul_rn(__fsub_rn(ax1, ax0), __fsub_rn(ay1, ay0));
    float areaB = __fmul_rn(__fsub_rn(bx1, bx0), __fsub_rn(by1, by0));
    float ltx = fmaxf(ax0, bx0), lty = fmaxf(ay0, by0);
    float rbx = fminf(ax1, bx1), rby = fminf(ay1, by1);
    float wx = fmaxf(__fsub_rn(rbx, ltx), 0.0f);
    float wy = fmaxf(__fsub_rn(rby, lty), 0.0f);
    float inter = __fmul_rn(wx, wy);
    float uni = __fsub_rn(__fadd_rn(areaA, areaB), inter);
    sm.nms.iou[e] = __fdiv_rn(inter, fmaxf(uni, 1e-9f));
  }
  __syncthreads();

  // sequential NMS inside wave 0 (shfl, no block barriers)
  if (tid < 64) {
    int keepA = 1;
    int keepB = 1;
    for (int i = 0; i < KSEL; i++) {
      int owner = i & 63;
      int ki = (i < 64) ? __shfl(keepA, owner) : __shfl(keepB, owner);
      if (ki) {
        if (tid > i && sm.nms.iou[i * KSEL + tid] > IOU_THRF) keepA = 0;
        int j = tid + 64;
        if (j < KSEL && j > i && sm.nms.iou[i * KSEL + j] > IOU_THRF) keepB = 0;
      }
    }
    sm.nms.keep[tid] = keepA;
    if (tid + 64 < KSEL) sm.nms.keep[tid + 64] = keepB;
  }
  __syncthreads();

  if (tid < KSEL) {
    float kp = (score > CONF_THRF && sm.nms.keep[tid]) ? 1.0f : 0.0f;
    out_keep[(size_t)b * KSEL + tid] = kp;
  }
}

extern "C" void kernel_launch(void* const* d_in, const int* in_sizes, int n_in,
                              void* d_out, int out_size, void* d_ws, size_t ws_size,
                              hipStream_t stream) {
  const float* logits = (const float*)d_in[0];   // (256, 900, 91) f32
  const float* pboxes = (const float*)d_in[1];   // (256, 900, 4)  f32
  const float* tsizes = (const float*)d_in[2];   // (256, 2)       f32
  (void)in_sizes; (void)n_in; (void)out_size;

  const size_t cnt_bytes = ((size_t)NBATCH * SLC * sizeof(uint32_t) + 255) & ~(size_t)255; // 25.6 KB
  const size_t need = cnt_bytes + (size_t)NBATCH * SLC * SCAP * sizeof(uint32_t);          // ~3.3 MB
  if (ws_size >= need) {
    uint32_t* cnts = (uint32_t*)d_ws;
    uint32_t* cand = (uint32_t*)((char*)d_ws + cnt_bytes);
    kfilter<<<NBATCH * SLC, ANT, 0, stream>>>(logits, cnts, cand);
    merge_nms<<<NBATCH, BNT, 0, stream>>>(cnts, cand, logits, pboxes, tsizes,
                                          (float*)d_out, 0);
  } else {
    // no workspace: exact (slow) fallback path, still correct
    merge_nms<<<NBATCH, BNT, 0, stream>>>(nullptr, nullptr, logits, pboxes, tsizes,
                                          (float*)d_out, 1);
  }
}

// Round 8
// 55.657 us; speedup vs baseline: 7.0425x; 1.0798x over previous
//
#include <hip/hip_runtime.h>
#include <stdint.h>

#define NBATCH 256
#define NQ 900
#define NC 91
#define NQC (NQ * NC)      // 81900
#define KSEL 100
#define IOU_THRF 0.7f
#define CONF_THRF 0.3f
#define TH_LOGIT 2.2f      // static filter; batch 100th logit ~3.03; verified in-kernel
#define DELTA 4096u        // key-ulp tie margin (~1e-3 logit; prob-rounding ties need ~1.3e-6)

// ---- kernel A: streaming filter, deterministic per-slice output ----
#define SLC 15             // slices per batch
#define SF4 1365           // float4 per slice (15*1365 = 20475 exact)
#define ANT 256
#define SCAP 128           // per-slice cap (expected ~76, 6-sigma margin)
#define CAPB (SLC * SCAP)  // 1920 max gathered per batch

// ---- kernel B: select + NMS ----
#define BNT 256
#define HBINS 64           // bin = (key>>20) - 0xC00, logit in [2.0, ~large); clamped
#define SRTCAP 512

// monotone key: ascending uint order == ascending float order
__device__ __forceinline__ uint32_t fkey(float x) {
  uint32_t b = __float_as_uint(x);
  return b ^ ((uint32_t)((int32_t)b >> 31) | 0x80000000u);
}
__device__ __forceinline__ float unfkey(uint32_t k) {
  uint32_t b = (k & 0x80000000u) ? (k ^ 0x80000000u) : ~k;
  return __uint_as_float(b);
}
__device__ __forceinline__ float sigmoidf_ref(float x) {
  return 1.0f / (1.0f + expf(-x));
}

// ======================= kernel A =======================
// Keep idx where logit >= TH_LOGIT. LDS compact buffer, then count + indices
// to this slice's PRIVATE region. No global atomics, no workspace init.
__global__ __launch_bounds__(ANT) void kfilter(const float* __restrict__ logits,
                                               uint32_t* __restrict__ cnts,
                                               uint32_t* __restrict__ cand) {
  __shared__ uint32_t lbuf[SCAP];
  __shared__ uint32_t lcnt;

  const int blk = blockIdx.x;            // b*SLC + s
  const int b = blk / SLC;
  const int s = blk - b * SLC;
  const int tid = threadIdx.x;
  const float4* lg4 = (const float4*)(logits + (size_t)b * NQC) + (size_t)s * SF4;

  if (tid == 0) lcnt = 0;
  __syncthreads();

  for (int i = tid; i < SF4; i += ANT) {
    float4 v = lg4[i];
    const uint32_t ibase = (uint32_t)((s * SF4 + i) * 4);
    if (v.x >= TH_LOGIT) { uint32_t p = atomicAdd(&lcnt, 1u); if (p < SCAP) lbuf[p] = ibase + 0; }
    if (v.y >= TH_LOGIT) { uint32_t p = atomicAdd(&lcnt, 1u); if (p < SCAP) lbuf[p] = ibase + 1; }
    if (v.z >= TH_LOGIT) { uint32_t p = atomicAdd(&lcnt, 1u); if (p < SCAP) lbuf[p] = ibase + 2; }
    if (v.w >= TH_LOGIT) { uint32_t p = atomicAdd(&lcnt, 1u); if (p < SCAP) lbuf[p] = ibase + 3; }
  }
  __syncthreads();
  const uint32_t m = lcnt;               // uniform; > SCAP signals fallback to B
  if (tid == 0) cnts[blk] = m;
  const uint32_t mw = m < SCAP ? m : SCAP;
  for (uint32_t i = tid; i < mw; i += ANT)
    cand[(size_t)blk * SCAP + i] = lbuf[i];
}

// ======================= kernel B =======================
union BSMem {
  struct {
    uint32_t idxs[CAPB];                          // 7.7 KB; reused as ranked u64[100] after compact
    uint32_t keys[CAPB];                          // 7.7 KB
    unsigned long long srt[SRTCAP];               // 4 KB survivor keys
  } p;
  struct {
    float iou[KSEL * KSEL];                       // 40 KB
    float box[KSEL][4];
    int keep[KSEL];
  } nms;
};

__global__ __launch_bounds__(BNT) void merge_nms(const uint32_t* __restrict__ cnts,
                                                 const uint32_t* __restrict__ cand,
                                                 const float* __restrict__ logits,
                                                 const float* __restrict__ pboxes,
                                                 const float* __restrict__ tsizes,
                                                 float* __restrict__ out,
                                                 int force_fallback) {
  __shared__ BSMem sm;
  __shared__ uint32_t scnt[SLC], soff[SLC];
  __shared__ uint32_t s_hist[HBINS];
  __shared__ uint32_t s_n, s_bad, s_cut, s_m;
  __shared__ unsigned long long red[BNT / 64];
  __shared__ unsigned long long s_last;

  const int b = blockIdx.x;
  const int tid = threadIdx.x;
  const float* lg = logits + (size_t)b * NQC;
  unsigned long long* ranked = (unsigned long long*)sm.p.idxs;  // aliases idxs (dead after compact)

  bool good = !force_fallback;
  if (good) {
    if (tid < SLC) scnt[tid] = cnts[b * SLC + tid];
    __syncthreads();
    if (tid == 0) {
      uint32_t off = 0, bad = 0;
      for (int i = 0; i < SLC; i++) {
        soff[i] = off;
        if (scnt[i] > SCAP) bad = 1;
        off += scnt[i];
      }
      s_n = off;
      s_bad = bad | (off < KSEL ? 1u : 0u);
    }
    __syncthreads();
    good = (s_bad == 0);
  }
  const uint32_t n = good ? s_n : 0;     // <= CAPB structurally

  if (good) {
    // gather slice regions into contiguous LDS list (wave w takes slices w, w+4, ...)
    const int wid = tid >> 6, lane = tid & 63;
    for (int sl = wid; sl < SLC; sl += BNT / 64) {
      const uint32_t c = scnt[sl], o = soff[sl];
      for (uint32_t j = lane; j < c; j += 64)
        sm.p.idxs[o + j] = cand[((size_t)b * SLC + sl) * SCAP + j];
    }
    if (tid < HBINS) s_hist[tid] = 0;
    if (tid == 0) s_m = 0;
    __syncthreads();

    // gather logits (L3-hot), key + 64-bin hist. All keys >= fkey(2.2) = 0xC00CCCCD.
    for (uint32_t i = tid; i < n; i += BNT) {
      uint32_t k = fkey(lg[sm.p.idxs[i]]);
      sm.p.keys[i] = k;
      uint32_t bin = (k >> 20) - 0xC00u;
      if (bin > HBINS - 1) bin = HBINS - 1;
      atomicAdd(&s_hist[bin], 1u);
    }
    __syncthreads();

    // wave-0 shfl suffix scan over 64 bins -> cut bin holding the batch 100th
    if (tid < 64) {
      uint32_t h = s_hist[tid];
      uint32_t suf = h;
      #pragma unroll
      for (int off = 1; off < 64; off <<= 1) {
        uint32_t t = __shfl_down(suf, off);
        if (tid + off < 64) suf += t;
      }
      bool pred = (suf >= KSEL) && (suf - h < KSEL);   // exactly one lane
      unsigned long long mask = __ballot(pred);
      int cutlane = __ffsll((long long)mask) - 1;      // -1 if none (defensive)
      if (tid == 0) s_cut = (uint32_t)cutlane;
    }
    __syncthreads();
    const uint32_t cut = s_cut;
    if (cut >= HBINS - 1) good = false;                // clamped/invalid bin
    const uint32_t thresh = ((cut + 0xC00u) << 20) - DELTA;

    if (good) {
      // compact survivors; sigmoid only here; key = (~pbits)<<32 | idx
      for (uint32_t i = tid; i < n; i += BNT) {
        uint32_t k = sm.p.keys[i];
        if (k >= thresh) {
          uint32_t pb = __float_as_uint(sigmoidf_ref(unfkey(k)));
          uint32_t pos = atomicAdd(&s_m, 1u);
          if (pos < SRTCAP)
            sm.p.srt[pos] = (((unsigned long long)(~pb)) << 32) |
                            (unsigned long long)sm.p.idxs[i];
        }
      }
      __syncthreads();
      const uint32_t m = s_m;
      if (m > SRTCAP) good = false;
      if (good) {
        // barrier-free rank selection: keys unique (idx embedded); ascending
        // rank r < KSEL == position in (prob desc, idx asc) order
        for (uint32_t s = tid; s < m; s += BNT) {
          unsigned long long mykey = sm.p.srt[s];
          uint32_t r = 0;
          for (uint32_t j = 0; j < m; j++)
            r += (sm.p.srt[j] < mykey) ? 1u : 0u;
          if (r < KSEL) ranked[r] = mykey;
        }
        __syncthreads();
      }
    }
  }

  if (!good) {
    // exact fallback (never taken on bench data): 100 rounds of block-wide
    // "next element in (prob desc, idx asc) order" over all 81900 logits.
    unsigned long long last = ~0ULL;
    for (int r = 0; r < KSEL; r++) {
      unsigned long long best = 0ULL;
      for (int i = tid; i < NQC; i += BNT) {
        uint32_t pb = __float_as_uint(sigmoidf_ref(lg[i]));
        unsigned long long cmp = (((unsigned long long)pb) << 32) |
                                 (unsigned long long)(~(uint32_t)i);
        if (cmp < last && cmp > best) best = cmp;
      }
      #pragma unroll
      for (int o = 32; o >= 1; o >>= 1) {
        unsigned long long other = __shfl_down(best, o);
        if (other > best) best = other;
      }
      if ((tid & 63) == 0) red[tid >> 6] = best;
      __syncthreads();
      if (tid == 0) {
        unsigned long long mx = red[0];
        for (int w = 1; w < BNT / 64; w++) if (red[w] > mx) mx = red[w];
        s_last = mx;
        uint32_t pb = (uint32_t)(mx >> 32);
        uint32_t id = ~(uint32_t)mx;
        ranked[r] = (((unsigned long long)(~pb)) << 32) | (unsigned long long)id;
      }
      __syncthreads();
      last = s_last;
    }
  }

  float score = 0.0f;
  int idx = 0;
  if (tid < KSEL) {
    unsigned long long key = ranked[tid];
    score = __uint_as_float(~(uint32_t)(key >> 32));
    idx = (int)(uint32_t)(key & 0xFFFFFFFFu);
  }
  __syncthreads();   // all ranked reads done before nms union reuse

  const float img_h = tsizes[b * 2 + 0];
  const float img_w = tsizes[b * 2 + 1];
  float* out_scores = out;
  float* out_labels = out + (size_t)NBATCH * KSEL;
  float* out_boxes  = out + (size_t)2 * NBATCH * KSEL;
  float* out_keep   = out + (size_t)2 * NBATCH * KSEL + (size_t)NBATCH * KSEL * 4;

  if (tid < KSEL) {
    int q = idx / NC;
    int lab = idx - q * NC;
    const float* pb = pboxes + ((size_t)b * NQ + q) * 4;
    float cx = pb[0], cy = pb[1], w = pb[2], h = pb[3];
    float hw = __fmul_rn(0.5f, w), hh = __fmul_rn(0.5f, h);
    float x0 = __fmul_rn(__fsub_rn(cx, hw), img_w);
    float y0 = __fmul_rn(__fsub_rn(cy, hh), img_h);
    float x1 = __fmul_rn(__fadd_rn(cx, hw), img_w);
    float y1 = __fmul_rn(__fadd_rn(cy, hh), img_h);
    out_scores[(size_t)b * KSEL + tid] = score;
    out_labels[(size_t)b * KSEL + tid] = (float)lab;
    float* ob = out_boxes + ((size_t)b * KSEL + tid) * 4;
    ob[0] = x0; ob[1] = y0; ob[2] = x1; ob[3] = y1;
    sm.nms.box[tid][0] = x0; sm.nms.box[tid][1] = y0;
    sm.nms.box[tid][2] = x1; sm.nms.box[tid][3] = y1;
  }
  __syncthreads();

  for (int e = tid; e < KSEL * KSEL; e += BNT) {
    int i = e / KSEL;
    int j = e - i * KSEL;
    float ax0 = sm.nms.box[i][0], ay0 = sm.nms.box[i][1];
    float ax1 = sm.nms.box[i][2], ay1 = sm.nms.box[i][3];
    float bx0 = sm.nms.box[j][0], by0 = sm.nms.box[j][1];
    float bx1 = sm.nms.box[j][2], by1 = sm.nms.box[j][3];
    float areaA = __fmul_rn(__fsub_rn(ax1, ax0), __fsub_rn(ay1, ay0));
    float areaB = __fmul_rn(__fsub_rn(bx1, bx0), __fsub_rn(by1, by0));
    float ltx = fmaxf(ax0, bx0), lty = fmaxf(ay0, by0);
    float rbx = fminf(ax1, bx1), rby = fminf(ay1, by1);
    float wx = fmaxf(__fsub_rn(rbx, ltx), 0.0f);
    float wy = fmaxf(__fsub_rn(rby, lty), 0.0f);
    float inter = __fmul_rn(wx, wy);
    float uni = __fsub_rn(__fadd_rn(areaA, areaB), inter);
    sm.nms.iou[e] = __fdiv_rn(inter, fmaxf(uni, 1e-9f));
  }
  __syncthreads();

  // sequential NMS inside wave 0 (shfl, no block barriers)
  if (tid < 64) {
    int keepA = 1;
    int keepB = 1;
    for (int i = 0; i < KSEL; i++) {
      int owner = i & 63;
      int ki = (i < 64) ? __shfl(keepA, owner) : __shfl(keepB, owner);
      if (ki) {
        if (tid > i && sm.nms.iou[i * KSEL + tid] > IOU_THRF) keepA = 0;
        int j = tid + 64;
        if (j < KSEL && j > i && sm.nms.iou[i * KSEL + j] > IOU_THRF) keepB = 0;
      }
    }
    sm.nms.keep[tid] = keepA;
    if (tid + 64 < KSEL) sm.nms.keep[tid + 64] = keepB;
  }
  __syncthreads();

  if (tid < KSEL) {
    float kp = (score > CONF_THRF && sm.nms.keep[tid]) ? 1.0f : 0.0f;
    out_keep[(size_t)b * KSEL + tid] = kp;
  }
}

extern "C" void kernel_launch(void* const* d_in, const int* in_sizes, int n_in,
                              void* d_out, int out_size, void* d_ws, size_t ws_size,
                              hipStream_t stream) {
  const float* logits = (const float*)d_in[0];   // (256, 900, 91) f32
  const float* pboxes = (const float*)d_in[1];   // (256, 900, 4)  f32
  const float* tsizes = (const float*)d_in[2];   // (256, 2)       f32
  (void)in_sizes; (void)n_in; (void)out_size;

  const size_t cnt_bytes = ((size_t)NBATCH * SLC * sizeof(uint32_t) + 255) & ~(size_t)255; // 15.4 KB
  const size_t need = cnt_bytes + (size_t)NBATCH * SLC * SCAP * sizeof(uint32_t);          // ~2 MB
  if (ws_size >= need) {
    uint32_t* cnts = (uint32_t*)d_ws;
    uint32_t* cand = (uint32_t*)((char*)d_ws + cnt_bytes);
    kfilter<<<NBATCH * SLC, ANT, 0, stream>>>(logits, cnts, cand);
    merge_nms<<<NBATCH, BNT, 0, stream>>>(cnts, cand, logits, pboxes, tsizes,
                                          (float*)d_out, 0);
  } else {
    // no workspace: exact (slow) fallback path, still correct
    merge_nms<<<NBATCH, BNT, 0, stream>>>(nullptr, nullptr, logits, pboxes, tsizes,
                                          (float*)d_out, 1);
  }
}